// Round 11
// baseline (173.366 us; speedup 1.0000x reference)
//
#include <hip/hip_runtime.h>
#include <hip/hip_bf16.h>

#define T_LEN 1000
#define B_N 8
#define IN_CH 80
#define CONV_CH 256
#define CCEP_N 222

typedef short s8v __attribute__((ext_vector_type(8)));    // 8 bf16 (4 VGPRs)
typedef float f16v __attribute__((ext_vector_type(16)));  // MFMA 32x32 acc

#define TWO_PI 6.28318530717958647692f

// ===================== fused prep kernel (weights + tables) ===================
// blocks [0,240): W1^T; [240,336): W2^T; [336,432): W3^T; [432,1200): W4 chunks;
// [1200,1206): twiddle (1020 float2) + window (512).
__global__ __launch_bounds__(256) void k_prep(
    const float* __restrict__ W1, const float* __restrict__ W2,
    const float* __restrict__ W3, const float* __restrict__ W4,
    float* __restrict__ Wt1, float* __restrict__ Wt2, float* __restrict__ Wt3,
    __hip_bfloat16* __restrict__ Wc, float2* __restrict__ twTab,
    float* __restrict__ winTab) {
  const int bid = blockIdx.x, tid = threadIdx.x;
  if (bid < 240) {
    int e = bid * 256 + tid;                 // 61440
    int o = e / 240, k = e - o * 240;
    Wt1[k * 256 + o] = W1[e];
  } else if (bid < 336) {
    int e = (bid - 240) * 256 + tid;         // 24576
    int o = e / 96, k = e - o * 96;
    Wt2[k * 256 + o] = W2[e];
  } else if (bid < 432) {
    int e = (bid - 336) * 256 + tid;
    int o = e / 96, k = e - o * 96;
    Wt3[k * 256 + o] = W3[e];
  } else if (bid < 1200) {
    int e = (bid - 432) * 256 + tid;         // 196608
    int kloc = e & 31, n = (e >> 5) & 255, chg = e >> 13;
    int kp = chg * 32 + kloc;
    int kappa = kp >> 8, i = kp & 255;
    float v = 0.f;
    if (n < CCEP_N) {
      float invq = 1.f / (float)((n < 111) ? (111 - n) : (n - 110));
      v = W4[n * 768 + i * 3 + kappa] * invq;
    }
    Wc[e] = __float2bfloat16(v);
  } else {
    int e = (bid - 1200) * 256 + tid;        // 0..1535
    if (e < 1020) {
      int Q, off;
      if (e < 768)       { Q = 256; off = 0; }
      else if (e < 960)  { Q = 64;  off = 768; }
      else if (e < 1008) { Q = 16;  off = 960; }
      else               { Q = 4;   off = 1008; }
      int rem = e - off;
      int r = rem / Q, pos = rem - r * Q;
      float ang = (TWO_PI * (float)((r + 1) * pos)) / (float)(4 * Q);
      float s, c;
      sincosf(ang, &s, &c);
      twTab[e] = make_float2(c, s);
    } else if (e < 1532) {
      int n = e - 1020;
      winTab[n] = (0.5f - 0.5f * cosf(TWO_PI * (float)n / 512.f)) * (1.f / 1024.f);
    }
  }
}

// ---------------- conv1: (B,T,80) -> (B,T,256), k=3 same, relu ----------------
__global__ __launch_bounds__(256) void k_conv1t(const float* __restrict__ x,
    const float* __restrict__ Wt, const float* __restrict__ bias,
    float* __restrict__ out) {
  const int b = blockIdx.y;
  const int t0 = blockIdx.x * 10;
  const int o = threadIdx.x;
  __shared__ float hs[IN_CH * 14];
  for (int e = threadIdx.x; e < 12 * IN_CH; e += 256) {
    int r = e / IN_CH, c = e - r * IN_CH;
    int t = t0 - 1 + r;
    hs[c * 14 + r] = (t >= 0 && t < T_LEN) ? x[(b * T_LEN + t) * IN_CH + c] : 0.f;
  }
  __syncthreads();
  float acc[10];
  float bv = bias[o];
#pragma unroll
  for (int j = 0; j < 10; j++) acc[j] = bv;
  for (int i = 0; i < IN_CH; i++) {
    float w0 = Wt[(3 * i + 0) * 256 + o];
    float w1 = Wt[(3 * i + 1) * 256 + o];
    float w2 = Wt[(3 * i + 2) * 256 + o];
    const float* row = &hs[i * 14];
    float a[12];
#pragma unroll
    for (int u = 0; u < 6; u++) *(float2*)&a[2 * u] = *(const float2*)(row + 2 * u);
#pragma unroll
    for (int j = 0; j < 10; j++) {
      acc[j] = fmaf(a[j], w0, acc[j]);
      acc[j] = fmaf(a[j + 1], w1, acc[j]);
      acc[j] = fmaf(a[j + 2], w2, acc[j]);
    }
  }
#pragma unroll
  for (int j = 0; j < 10; j++)
    out[(b * T_LEN + t0 + j) * CONV_CH + o] = fmaxf(acc[j], 0.f);
}

// ----- fused double grouped conv: h1 -> (h2 in LDS) -> h3 bf16, groups=8 ------
// h2 rows with t outside [0,T_LEN) are ZEROED (reference zero-pads layer-3 in).
__global__ __launch_bounds__(256) void k_convg2(const float* __restrict__ h,
    const float* __restrict__ Wt2, const float* __restrict__ b2,
    const float* __restrict__ Wt3, const float* __restrict__ b3,
    __hip_bfloat16* __restrict__ out) {
  const int b = blockIdx.y;
  const int t0 = blockIdx.x * 10;
  const int o = threadIdx.x;
  const int cb = (o >> 5) << 5;
  __shared__ float hs1[CONV_CH * 14];
  __shared__ float hs2[CONV_CH * 14];
  for (int e = threadIdx.x; e < 14 * CONV_CH; e += 256) {
    int r = e >> 8, c = e & 255;
    int t = t0 - 2 + r;
    hs1[c * 14 + r] = (t >= 0 && t < T_LEN) ? h[(b * T_LEN + t) * CONV_CH + c] : 0.f;
  }
  __syncthreads();
  {
    float acc[12];
    float bv = b2[o];
#pragma unroll
    for (int j = 0; j < 12; j++) acc[j] = bv;
    for (int i = 0; i < 32; i++) {
      float w0 = Wt2[(3 * i + 0) * 256 + o];
      float w1 = Wt2[(3 * i + 1) * 256 + o];
      float w2 = Wt2[(3 * i + 2) * 256 + o];
      const float* row = &hs1[(cb + i) * 14];
      float a[14];
#pragma unroll
      for (int u = 0; u < 7; u++) *(float2*)&a[2 * u] = *(const float2*)(row + 2 * u);
#pragma unroll
      for (int j = 0; j < 12; j++) {
        acc[j] = fmaf(a[j], w0, acc[j]);
        acc[j] = fmaf(a[j + 1], w1, acc[j]);
        acc[j] = fmaf(a[j + 2], w2, acc[j]);
      }
    }
#pragma unroll
    for (int j = 0; j < 12; j++) {
      int t = t0 - 1 + j;
      hs2[o * 14 + j] = (t >= 0 && t < T_LEN) ? fmaxf(acc[j], 0.f) : 0.f;
    }
  }
  __syncthreads();
  {
    float acc[10];
    float bv = b3[o];
#pragma unroll
    for (int j = 0; j < 10; j++) acc[j] = bv;
    for (int i = 0; i < 32; i++) {
      float w0 = Wt3[(3 * i + 0) * 256 + o];
      float w1 = Wt3[(3 * i + 1) * 256 + o];
      float w2 = Wt3[(3 * i + 2) * 256 + o];
      const float* row = &hs2[(cb + i) * 14];
      float a[12];
#pragma unroll
      for (int u = 0; u < 6; u++) *(float2*)&a[2 * u] = *(const float2*)(row + 2 * u);
#pragma unroll
      for (int j = 0; j < 10; j++) {
        acc[j] = fmaf(a[j], w0, acc[j]);
        acc[j] = fmaf(a[j + 1], w1, acc[j]);
        acc[j] = fmaf(a[j + 2], w2, acc[j]);
      }
    }
#pragma unroll
    for (int j = 0; j < 10; j++)
      out[(b * T_LEN + t0 + j) * CONV_CH + o] = __float2bfloat16(fmaxf(acc[j], 0.f));
  }
}

// ============ conv4 as MFMA GEMM, K-split x4: 512 blocks (2/CU) ===============
#define APITCH 264
#define BPITCH 40
#define PSTRIDE 1792000
__global__ __launch_bounds__(256) void k_conv4m(
    const __hip_bfloat16* __restrict__ h3, const __hip_bfloat16* __restrict__ Wc,
    const float* __restrict__ bias, float* __restrict__ Pbase) {
  const int mb = blockIdx.x, b = blockIdx.y, ks = blockIdx.z;
  float* __restrict__ P = Pbase + (size_t)ks * PSTRIDE;
  const int t0 = mb * 64;
  const int tid = threadIdx.x;
  const int w = tid >> 6, lane = tid & 63;
  const int wm = w >> 1, wn = w & 1;
  const int lm = lane & 31, half = lane >> 5;

  __shared__ short h3s[67 * APITCH];
  __shared__ short Bs[2][256 * BPITCH];

  const ushort* h3u = (const ushort*)h3;
  for (int g = tid; g < 67 * 64; g += 256) {
    int rr = g >> 6, c4 = g & 63;
    int t = t0 + rr - 1;
    uint2 v = make_uint2(0u, 0u);
    if (t >= 0 && t < T_LEN)
      v = *(const uint2*)(h3u + (b * T_LEN + t) * CONV_CH + c4 * 4);
    *(uint2*)(h3s + rr * APITCH + c4 * 4) = v;
  }

  const ushort* Wu = (const ushort*)(Wc) + (size_t)(ks * 6) * 8192;
#pragma unroll
  for (int it = 0; it < 4; ++it) {
    int idx = (it * 256 + tid) * 8;
    uint4 v = *(const uint4*)(Wu + idx);
    int n = idx >> 5, kloc = idx & 31;
    *(uint4*)(Bs[0] + n * BPITCH + kloc) = v;
  }
  __syncthreads();

  f16v acc0 = {}, acc1 = {}, acc2 = {}, acc3 = {};

  for (int ch = 0; ch < 6; ++ch) {
    const int p = ch & 1;
    if (ch < 5) {
      const ushort* src = Wu + (ch + 1) * 8192;
#pragma unroll
      for (int it = 0; it < 4; ++it) {
        int idx = (it * 256 + tid) * 8;
        uint4 v = *(const uint4*)(src + idx);
        int n = idx >> 5, kloc = idx & 31;
        *(uint4*)(Bs[p ^ 1] + n * BPITCH + kloc) = v;
      }
    }
#pragma unroll
    for (int s = 0; s < 2; ++s) {
      int k0 = ks * 192 + ch * 32 + s * 16;
      int kappa = k0 >> 8, i0 = k0 & 255;
      s8v a = *(const s8v*)(h3s + (wm * 32 + lm + kappa) * APITCH + i0 + half * 8);
      const short* bp = Bs[p] + (wn * 128 + lm) * BPITCH + s * 16 + half * 8;
      s8v b0 = *(const s8v*)(bp);
      s8v b1 = *(const s8v*)(bp + 32 * BPITCH);
      s8v b2 = *(const s8v*)(bp + 64 * BPITCH);
      s8v b3 = *(const s8v*)(bp + 96 * BPITCH);
      acc0 = __builtin_amdgcn_mfma_f32_32x32x16_bf16(a, b0, acc0, 0, 0, 0);
      acc1 = __builtin_amdgcn_mfma_f32_32x32x16_bf16(a, b1, acc1, 0, 0, 0);
      acc2 = __builtin_amdgcn_mfma_f32_32x32x16_bf16(a, b2, acc2, 0, 0, 0);
      acc3 = __builtin_amdgcn_mfma_f32_32x32x16_bf16(a, b3, acc3, 0, 0, 0);
    }
    __syncthreads();
  }

  const int col = lm;
#pragma unroll
  for (int nt = 0; nt < 4; ++nt) {
    int c = wn * 128 + nt * 32 + col;
    if (c >= CCEP_N) continue;
    float bq = 0.f;
    if (ks == 0) {
      float invq = 1.f / (float)((c < 111) ? (111 - c) : (c - 110));
      bq = bias[c] * invq;
    }
    const f16v* A = (nt == 0) ? &acc0 : (nt == 1) ? &acc1 : (nt == 2) ? &acc2 : &acc3;
#pragma unroll
    for (int reg = 0; reg < 16; ++reg) {
      int row = (reg & 3) + 8 * (reg >> 2) + 4 * half;
      int t = t0 + wm * 32 + row;
      if (t < T_LEN)
        P[(size_t)(b * T_LEN + t) * 224 + c] = (*A)[reg] + bq;
    }
  }
}

// ============================ fused FFT kernel (2 frames/block) ===============
// Frames tA=2u, tB=2u+1. Two packed forward FFTs (c + i*fr per frame); S_A, S_B
// Hermitian -> ONE inverse: Z = S_A + i*S_B, IFFT(Z) = C_A + i*C_B (both real).
// Output: row tB (odd) fully owned -> plain store. Even-row contributions go to
// side buffers (plain stores); k_even combines. NO atomics anywhere.
__device__ __forceinline__ float2 cmul(float2 a, float2 b) {
  return make_float2(fmaf(a.x, b.x, -(a.y * b.y)), fmaf(a.x, b.y, a.y * b.x));
}
__device__ __forceinline__ float2 cadd(float2 a, float2 b) { return make_float2(a.x + b.x, a.y + b.y); }
__device__ __forceinline__ float2 csub(float2 a, float2 b) { return make_float2(a.x - b.x, a.y - b.y); }

#define LIDX(i) ((i) + ((i) >> 2))

template <int Q, int OFF>
__device__ __forceinline__ void fwd_stage2(float2* __restrict__ A,
    float2* __restrict__ B, const float2* __restrict__ Tw, int j) {
  const int pos = j & (Q - 1);
  const int base = ((j - pos) << 2) + pos;
  float2 e1 = Tw[OFF + pos], e2 = Tw[OFF + Q + pos], e3 = Tw[OFF + 2 * Q + pos];
  const float2 w1 = make_float2(e1.x, -e1.y);
  const float2 w2 = make_float2(e2.x, -e2.y);
  const float2 w3 = make_float2(e3.x, -e3.y);
#pragma unroll
  for (int arr = 0; arr < 2; ++arr) {
    float2* X = arr ? B : A;
    float2 a = X[LIDX(base)], b = X[LIDX(base + Q)];
    float2 cc = X[LIDX(base + 2 * Q)], d = X[LIDX(base + 3 * Q)];
    float2 t0 = cadd(a, cc), t1 = csub(a, cc), t2 = cadd(b, d), bd = csub(b, d);
    float2 t3 = make_float2(bd.y, -bd.x);
    X[LIDX(base)]         = cadd(t0, t2);
    X[LIDX(base + Q)]     = cmul(cadd(t1, t3), w1);
    X[LIDX(base + 2 * Q)] = cmul(csub(t0, t2), w2);
    X[LIDX(base + 3 * Q)] = cmul(csub(t1, t3), w3);
  }
}

template <int Q, int OFF>
__device__ __forceinline__ void inv_stage_t(float2* __restrict__ X,
    const float2* __restrict__ Tw, int j) {
  const int pos = j & (Q - 1);
  const int base = ((j - pos) << 2) + pos;
  const float2 w1 = Tw[OFF + pos];
  const float2 w2 = Tw[OFF + Q + pos];
  const float2 w3 = Tw[OFF + 2 * Q + pos];
  float2 a = X[LIDX(base)];
  float2 b = cmul(X[LIDX(base + Q)], w1);
  float2 cc = cmul(X[LIDX(base + 2 * Q)], w2);
  float2 d = cmul(X[LIDX(base + 3 * Q)], w3);
  float2 t0 = cadd(a, cc), t1 = csub(a, cc), t2 = cadd(b, d), bd = csub(b, d);
  float2 t3 = make_float2(-bd.y, bd.x);
  X[LIDX(base)]         = cadd(t0, t2);
  X[LIDX(base + Q)]     = cadd(t1, t3);
  X[LIDX(base + 2 * Q)] = csub(t0, t2);
  X[LIDX(base + 3 * Q)] = csub(t1, t3);
}

__device__ __forceinline__ int rev4d(int v) {
  return ((v & 3) << 6) | (((v >> 2) & 3) << 4) | (((v >> 4) & 3) << 2) | ((v >> 6) & 3);
}

// grid (500, 8)
__global__ __launch_bounds__(256) void k_fft(const float* __restrict__ Pb,
    const float* __restrict__ z, const float2* __restrict__ twg,
    const float* __restrict__ wing, float* __restrict__ out,
    float* __restrict__ sbl, float* __restrict__ sbr) {
  const int u = blockIdx.x, b = blockIdx.y;
  const int tA = 2 * u, tB = tA + 1;
  const int btA = b * T_LEN + tA, btB = btA + 1;
  const int j = threadIdx.x;
  __shared__ float2 WlA[1280];
  __shared__ float2 WlB[1280];
  __shared__ float2 Tws[1020];
  for (int e = j; e < 1020; e += 256) Tws[e] = twg[e];

  const float* zb = z + b * 256000;
  float f0A = 0.f, fS, f1B = 0.f;
  {
    int zi0 = tA * 256 + j - 255;
    f0A = (zi0 >= 0) ? zb[zi0] : 0.f;
    fS = zb[tA * 256 + j + 1];
    int zi2 = tB * 256 + j + 1;
    f1B = (zi2 < 256000) ? zb[zi2] : 0.f;
  }
  float c1A = 0.f, c2A = 0.f, c1B = 0.f, c2B = 0.f;
  if (j >= 145) {
    int mA = btA * 224 + (j - 145), mB = btB * 224 + (j - 145);
    c1A = (Pb[mA] + Pb[mA + PSTRIDE]) + (Pb[mA + 2 * PSTRIDE] + Pb[mA + 3 * PSTRIDE]);
    c1B = (Pb[mB] + Pb[mB + PSTRIDE]) + (Pb[mB + 2 * PSTRIDE] + Pb[mB + 3 * PSTRIDE]);
  }
  if (j < 111) {
    int mA = btA * 224 + (j + 111), mB = btB * 224 + (j + 111);
    c2A = (Pb[mA] + Pb[mA + PSTRIDE]) + (Pb[mA + 2 * PSTRIDE] + Pb[mA + 3 * PSTRIDE]);
    c2B = (Pb[mB] + Pb[mB + PSTRIDE]) + (Pb[mB + 2 * PSTRIDE] + Pb[mB + 3 * PSTRIDE]);
  }
  __syncthreads();

  {
    float2 e1 = Tws[j], e2 = Tws[256 + j], e3 = Tws[512 + j];
    const float2 w1 = make_float2(e1.x, -e1.y);
    const float2 w2 = make_float2(e2.x, -e2.y);
    const float2 w3 = make_float2(e3.x, -e3.y);
    {
      float2 t0 = make_float2(c2A, f0A);
      float2 t1 = make_float2(-c2A, f0A);
      float2 t2 = make_float2(c1A, fS);
      float2 t3 = make_float2(fS, -c1A);
      WlA[LIDX(j)]       = cadd(t0, t2);
      WlA[LIDX(j + 256)] = cmul(cadd(t1, t3), w1);
      WlA[LIDX(j + 512)] = cmul(csub(t0, t2), w2);
      WlA[LIDX(j + 768)] = cmul(csub(t1, t3), w3);
    }
    {
      float2 t0 = make_float2(c2B, fS);
      float2 t1 = make_float2(-c2B, fS);
      float2 t2 = make_float2(c1B, f1B);
      float2 t3 = make_float2(f1B, -c1B);
      WlB[LIDX(j)]       = cadd(t0, t2);
      WlB[LIDX(j + 256)] = cmul(cadd(t1, t3), w1);
      WlB[LIDX(j + 512)] = cmul(csub(t0, t2), w2);
      WlB[LIDX(j + 768)] = cmul(csub(t1, t3), w3);
    }
  }
  __syncthreads();

  fwd_stage2<64, 768>(WlA, WlB, Tws, j);  __syncthreads();
  fwd_stage2<16, 960>(WlA, WlB, Tws, j);  __syncthreads();
  fwd_stage2<4, 1008>(WlA, WlB, Tws, j);  __syncthreads();

  const int base = 4 * j;
  float2 XA[4], XB[4];
  {
    float2 u0 = WlA[LIDX(base)], u1 = WlA[LIDX(base + 1)];
    float2 u2 = WlA[LIDX(base + 2)], u3 = WlA[LIDX(base + 3)];
    float2 t0 = cadd(u0, u2), t1 = csub(u0, u2), t2 = cadd(u1, u3), bd = csub(u1, u3);
    float2 t3 = make_float2(bd.y, -bd.x);
    XA[0] = cadd(t0, t2); XA[1] = cadd(t1, t3); XA[2] = csub(t0, t2); XA[3] = csub(t1, t3);
  }
  {
    float2 u0 = WlB[LIDX(base)], u1 = WlB[LIDX(base + 1)];
    float2 u2 = WlB[LIDX(base + 2)], u3 = WlB[LIDX(base + 3)];
    float2 t0 = cadd(u0, u2), t1 = csub(u0, u2), t2 = cadd(u1, u3), bd = csub(u1, u3);
    float2 t3 = make_float2(bd.y, -bd.x);
    XB[0] = cadd(t0, t2); XB[1] = cadd(t1, t3); XB[2] = csub(t0, t2); XB[3] = csub(t1, t3);
  }
#pragma unroll
  for (int q = 0; q < 4; ++q) { WlA[LIDX(base + q)] = XA[q]; WlB[LIDX(base + q)] = XB[q]; }
  __syncthreads();

  const int r0 = rev4d(j);
  const bool self0 = (r0 == 0);
  const int jp = self0 ? 0 : rev4d((256 - r0) & 255);
  float2 PA[4], PB[4];
#pragma unroll
  for (int q = 0; q < 4; ++q) { PA[q] = WlA[LIDX(4 * jp + q)]; PB[q] = WlB[LIDX(4 * jp + q)]; }
  float2 Z[4];
#pragma unroll
  for (int q = 0; q < 4; ++q) {
    float2 SA, SB;
    {
      float2 A = XA[q];
      float2 Bc = self0 ? PA[(4 - q) & 3] : PA[3 - q];
      float2 Y = make_float2(0.5f * (A.x + Bc.x), 0.5f * (A.y - Bc.y));
      float2 F = make_float2(0.5f * (A.y + Bc.y), -0.5f * (A.x - Bc.x));
      float mag = __expf(Y.x * 2.30258509299404568402f);
      float sy, cy;
      __sincosf(Y.y, &sy, &cy);
      float gr = mag * cy, gi = mag * sy;
      SA = make_float2(fmaf(F.x, gr, F.y * gi), fmaf(F.x, gi, -(F.y * gr)));
    }
    {
      float2 A = XB[q];
      float2 Bc = self0 ? PB[(4 - q) & 3] : PB[3 - q];
      float2 Y = make_float2(0.5f * (A.x + Bc.x), 0.5f * (A.y - Bc.y));
      float2 F = make_float2(0.5f * (A.y + Bc.y), -0.5f * (A.x - Bc.x));
      float mag = __expf(Y.x * 2.30258509299404568402f);
      float sy, cy;
      __sincosf(Y.y, &sy, &cy);
      float gr = mag * cy, gi = mag * sy;
      SB = make_float2(fmaf(F.x, gr, F.y * gi), fmaf(F.x, gi, -(F.y * gr)));
    }
    Z[q] = make_float2(SA.x - SB.y, SA.y + SB.x);   // S_A + i*S_B
  }
  __syncthreads();

  {
    float2 t0 = cadd(Z[0], Z[2]), t1 = csub(Z[0], Z[2]), t2 = cadd(Z[1], Z[3]), bd = csub(Z[1], Z[3]);
    float2 t3 = make_float2(-bd.y, bd.x);
    WlA[LIDX(base)]     = cadd(t0, t2);
    WlA[LIDX(base + 1)] = cadd(t1, t3);
    WlA[LIDX(base + 2)] = csub(t0, t2);
    WlA[LIDX(base + 3)] = csub(t1, t3);
  }
  __syncthreads();

  inv_stage_t<4, 1008>(WlA, Tws, j);  __syncthreads();
  inv_stage_t<16, 960>(WlA, Tws, j);  __syncthreads();
  inv_stage_t<64, 768>(WlA, Tws, j);  __syncthreads();

  {
    float2 w1 = Tws[j], w2 = Tws[256 + j], w3 = Tws[512 + j];
    float2 a = WlA[LIDX(j)];
    float2 bb = cmul(WlA[LIDX(j + 256)], w1);
    float2 cc = cmul(WlA[LIDX(j + 512)], w2);
    float2 d = cmul(WlA[LIDX(j + 768)], w3);
    float2 t0 = cadd(a, cc), t1 = csub(a, cc), t2 = cadd(bb, d), bd = csub(bb, d);
    float2 t3 = make_float2(-bd.y, bd.x);
    float2 Cj    = cadd(t0, t2);   // C[j]     -> corr n1 = 511-j (r-part)
    float2 Cj256 = cadd(t1, t3);   // C[j+256] -> corr n2 = 255-j (l-part)
    int n1 = 511 - j, n2 = 255 - j;
    float wn1 = wing[n1], wn2 = wing[n2];
    float vA_l = Cj256.x * wn2;                 // even row tA contribution (l)
    float vAB  = Cj.x * wn1 + Cj256.y * wn2;    // odd row tB: A.r + B.l (owned)
    float vB_r = Cj.y * wn1;                    // even row tB+1 contribution (r)
    out[(b * T_LEN + tB) * 256 + n2] = vAB;     // plain store, single writer
    int su = (b * 500 + u) * 256 + n2;
    sbl[su] = vA_l;
    sbr[su] = vB_r;
  }
}

// ---- even rows: out[b, 2u, n] = l(2u) + r(2u-1 mod 1000) ---------------------
__global__ __launch_bounds__(256) void k_even(const float* __restrict__ sbl,
    const float* __restrict__ sbr, float* __restrict__ out) {
  int idx = blockIdx.x * 256 + threadIdx.x;   // 1,024,000
  int n = idx & 255;
  int bu = idx >> 8;                          // b*500 + u
  int u = bu % 500, b = bu / 500;
  int up = (u == 0) ? 499 : u - 1;
  out[(b * T_LEN + 2 * u) * 256 + n] = sbl[idx] + sbr[(b * 500 + up) * 256 + n];
}

extern "C" void kernel_launch(void* const* d_in, const int* in_sizes, int n_in,
                              void* d_out, int out_size, void* d_ws, size_t ws_size,
                              hipStream_t stream) {
  const float* x  = (const float*)d_in[0];
  const float* z  = (const float*)d_in[1];
  const float* W1 = (const float*)d_in[2];
  const float* b1 = (const float*)d_in[3];
  const float* W2 = (const float*)d_in[4];
  const float* b2 = (const float*)d_in[5];
  const float* W3 = (const float*)d_in[6];
  const float* b3 = (const float*)d_in[7];
  const float* W4 = (const float*)d_in[8];
  const float* b4 = (const float*)d_in[9];

  float* ws   = (float*)d_ws;
  float* bufA = ws;                      // 2,048,000 (h1)
  __hip_bfloat16* h3bf = (__hip_bfloat16*)(ws + 2048000);  // 1,024,000 f32 slots
  float* Pb   = ws + 3072000;            // 4 x 1,792,000 = 7,168,000
  float* sbl  = ws + 10240000;           // 1,024,000
  float* sbr  = ws + 11264000;           // 1,024,000
  float* Wt1  = ws + 12288000;           //    61,440
  float* Wt2  = ws + 12349440;           //    24,576
  float* Wt3  = ws + 12374016;           //    24,576
  __hip_bfloat16* Wc = (__hip_bfloat16*)(ws + 12398592);   // 98,304 f32 slots
  float2* twTab = (float2*)(ws + 12496896);                // 1020 float2
  float* winTab = ws + 12498944;                           // 512
  float* out = (float*)d_out;

  dim3 blk(256);
  k_prep<<<1206, blk, 0, stream>>>(W1, W2, W3, W4, Wt1, Wt2, Wt3, Wc,
                                   twTab, winTab);

  dim3 cgrid10(T_LEN / 10, B_N);   // (100, 8)
  k_conv1t<<<cgrid10, blk, 0, stream>>>(x, Wt1, b1, bufA);
  k_convg2<<<cgrid10, blk, 0, stream>>>(bufA, Wt2, b2, Wt3, b3, h3bf);
  dim3 g4(16, B_N, 4);
  k_conv4m<<<g4, blk, 0, stream>>>(h3bf, Wc, b4, Pb);
  dim3 gf(T_LEN / 2, B_N);         // (500, 8)
  k_fft<<<gf, blk, 0, stream>>>(Pb, z, twTab, winTab, out, sbl, sbr);
  k_even<<<4000, blk, 0, stream>>>(sbl, sbr, out);
}

// Round 12
// 172.104 us; speedup vs baseline: 1.0073x; 1.0073x over previous
//
#include <hip/hip_runtime.h>
#include <hip/hip_bf16.h>

#define T_LEN 1000
#define B_N 8
#define IN_CH 80
#define CONV_CH 256
#define CCEP_N 222

typedef short s8v __attribute__((ext_vector_type(8)));    // 8 bf16 (4 VGPRs)
typedef float f16v __attribute__((ext_vector_type(16)));  // MFMA 32x32 acc

#define TWO_PI 6.28318530717958647692f

// ===================== fused prep kernel (weights + tables) ===================
// blocks [0,240): W1^T; [240,336): W2^T; [336,432): W3^T; [432,1200): W4 chunks;
// [1200,1206): twiddle (1020 float2) + window (512).
__global__ __launch_bounds__(256) void k_prep(
    const float* __restrict__ W1, const float* __restrict__ W2,
    const float* __restrict__ W3, const float* __restrict__ W4,
    float* __restrict__ Wt1, float* __restrict__ Wt2, float* __restrict__ Wt3,
    __hip_bfloat16* __restrict__ Wc, float2* __restrict__ twTab,
    float* __restrict__ winTab) {
  const int bid = blockIdx.x, tid = threadIdx.x;
  if (bid < 240) {
    int e = bid * 256 + tid;                 // 61440
    int o = e / 240, k = e - o * 240;
    Wt1[k * 256 + o] = W1[e];
  } else if (bid < 336) {
    int e = (bid - 240) * 256 + tid;         // 24576
    int o = e / 96, k = e - o * 96;
    Wt2[k * 256 + o] = W2[e];
  } else if (bid < 432) {
    int e = (bid - 336) * 256 + tid;
    int o = e / 96, k = e - o * 96;
    Wt3[k * 256 + o] = W3[e];
  } else if (bid < 1200) {
    int e = (bid - 432) * 256 + tid;         // 196608
    int kloc = e & 31, n = (e >> 5) & 255, chg = e >> 13;
    int kp = chg * 32 + kloc;
    int kappa = kp >> 8, i = kp & 255;
    float v = 0.f;
    if (n < CCEP_N) {
      float invq = 1.f / (float)((n < 111) ? (111 - n) : (n - 110));
      v = W4[n * 768 + i * 3 + kappa] * invq;
    }
    Wc[e] = __float2bfloat16(v);
  } else {
    int e = (bid - 1200) * 256 + tid;        // 0..1535
    if (e < 1020) {
      int Q, off;
      if (e < 768)       { Q = 256; off = 0; }
      else if (e < 960)  { Q = 64;  off = 768; }
      else if (e < 1008) { Q = 16;  off = 960; }
      else               { Q = 4;   off = 1008; }
      int rem = e - off;
      int r = rem / Q, pos = rem - r * Q;
      float ang = (TWO_PI * (float)((r + 1) * pos)) / (float)(4 * Q);
      float s, c;
      sincosf(ang, &s, &c);
      twTab[e] = make_float2(c, s);
    } else if (e < 1532) {
      int n = e - 1020;
      winTab[n] = (0.5f - 0.5f * cosf(TWO_PI * (float)n / 512.f)) * (1.f / 1024.f);
    }
  }
}

// ===== fully fused conv stack: x -> h1 (LDS) -> h2 (LDS) -> h3 bf16 ===========
// TT=10. x rows t0-3..t0+12 (16, pitch 18); h1 rows t0-2..t0+11 (14, zeroed
// outside [0,T)); h2 rows t0-1..t0+10 (12, zeroed outside); h3 rows t0..t0+9.
// Zeroing mirrors the reference's zero-padded "same" convs at every layer.
__global__ __launch_bounds__(256) void k_convall(const float* __restrict__ x,
    const float* __restrict__ Wt1, const float* __restrict__ b1,
    const float* __restrict__ Wt2, const float* __restrict__ b2,
    const float* __restrict__ Wt3, const float* __restrict__ b3,
    __hip_bfloat16* __restrict__ out) {
  const int b = blockIdx.y;
  const int t0 = blockIdx.x * 10;
  const int o = threadIdx.x;
  const int cb = (o >> 5) << 5;
  __shared__ float xs[IN_CH * 18];      // 16 rows used; pitch 18 (2-way free)
  __shared__ float hs1[CONV_CH * 14];
  __shared__ float hs2[CONV_CH * 14];
  for (int e = threadIdx.x; e < 16 * IN_CH; e += 256) {
    int r = e / IN_CH, c = e - r * IN_CH;
    int t = t0 - 3 + r;
    xs[c * 18 + r] = (t >= 0 && t < T_LEN) ? x[(b * T_LEN + t) * IN_CH + c] : 0.f;
  }
  __syncthreads();
  // ---- layer 1: h1 rows rr=0..13 (t = t0-2+rr) ----
  {
    float acc[14];
    float bv = b1[o];
#pragma unroll
    for (int j = 0; j < 14; j++) acc[j] = bv;
    for (int i = 0; i < IN_CH; i++) {
      float w0 = Wt1[(3 * i + 0) * 256 + o];
      float w1 = Wt1[(3 * i + 1) * 256 + o];
      float w2 = Wt1[(3 * i + 2) * 256 + o];
      const float* row = &xs[i * 18];
      float a[16];
#pragma unroll
      for (int u = 0; u < 8; u++) *(float2*)&a[2 * u] = *(const float2*)(row + 2 * u);
#pragma unroll
      for (int j = 0; j < 14; j++) {
        acc[j] = fmaf(a[j], w0, acc[j]);
        acc[j] = fmaf(a[j + 1], w1, acc[j]);
        acc[j] = fmaf(a[j + 2], w2, acc[j]);
      }
    }
#pragma unroll
    for (int j = 0; j < 14; j++) {
      int t = t0 - 2 + j;
      hs1[o * 14 + j] = (t >= 0 && t < T_LEN) ? fmaxf(acc[j], 0.f) : 0.f;
    }
  }
  __syncthreads();
  // ---- layer 2: h2 rows j=0..11 (t = t0-1+j), h1 idx j..j+2 ----
  {
    float acc[12];
    float bv = b2[o];
#pragma unroll
    for (int j = 0; j < 12; j++) acc[j] = bv;
    for (int i = 0; i < 32; i++) {
      float w0 = Wt2[(3 * i + 0) * 256 + o];
      float w1 = Wt2[(3 * i + 1) * 256 + o];
      float w2 = Wt2[(3 * i + 2) * 256 + o];
      const float* row = &hs1[(cb + i) * 14];
      float a[14];
#pragma unroll
      for (int u = 0; u < 7; u++) *(float2*)&a[2 * u] = *(const float2*)(row + 2 * u);
#pragma unroll
      for (int j = 0; j < 12; j++) {
        acc[j] = fmaf(a[j], w0, acc[j]);
        acc[j] = fmaf(a[j + 1], w1, acc[j]);
        acc[j] = fmaf(a[j + 2], w2, acc[j]);
      }
    }
    __syncthreads();   // hs1 reads done before hs2 write (distinct arrays; safe)
#pragma unroll
    for (int j = 0; j < 12; j++) {
      int t = t0 - 1 + j;
      hs2[o * 14 + j] = (t >= 0 && t < T_LEN) ? fmaxf(acc[j], 0.f) : 0.f;
    }
  }
  __syncthreads();
  // ---- layer 3: h3 rows j=0..9 (t = t0+j), h2 idx j..j+2 ----
  {
    float acc[10];
    float bv = b3[o];
#pragma unroll
    for (int j = 0; j < 10; j++) acc[j] = bv;
    for (int i = 0; i < 32; i++) {
      float w0 = Wt3[(3 * i + 0) * 256 + o];
      float w1 = Wt3[(3 * i + 1) * 256 + o];
      float w2 = Wt3[(3 * i + 2) * 256 + o];
      const float* row = &hs2[(cb + i) * 14];
      float a[12];
#pragma unroll
      for (int u = 0; u < 6; u++) *(float2*)&a[2 * u] = *(const float2*)(row + 2 * u);
#pragma unroll
      for (int j = 0; j < 10; j++) {
        acc[j] = fmaf(a[j], w0, acc[j]);
        acc[j] = fmaf(a[j + 1], w1, acc[j]);
        acc[j] = fmaf(a[j + 2], w2, acc[j]);
      }
    }
#pragma unroll
    for (int j = 0; j < 10; j++)
      out[(b * T_LEN + t0 + j) * CONV_CH + o] = __float2bfloat16(fmaxf(acc[j], 0.f));
  }
}

// ============ conv4 as MFMA GEMM, K-split x4: 512 blocks (2/CU) ===============
#define APITCH 264
#define BPITCH 40
#define PSTRIDE 1792000
__global__ __launch_bounds__(256) void k_conv4m(
    const __hip_bfloat16* __restrict__ h3, const __hip_bfloat16* __restrict__ Wc,
    const float* __restrict__ bias, float* __restrict__ Pbase) {
  const int mb = blockIdx.x, b = blockIdx.y, ks = blockIdx.z;
  float* __restrict__ P = Pbase + (size_t)ks * PSTRIDE;
  const int t0 = mb * 64;
  const int tid = threadIdx.x;
  const int w = tid >> 6, lane = tid & 63;
  const int wm = w >> 1, wn = w & 1;
  const int lm = lane & 31, half = lane >> 5;

  __shared__ short h3s[67 * APITCH];
  __shared__ short Bs[2][256 * BPITCH];

  const ushort* h3u = (const ushort*)h3;
  for (int g = tid; g < 67 * 64; g += 256) {
    int rr = g >> 6, c4 = g & 63;
    int t = t0 + rr - 1;
    uint2 v = make_uint2(0u, 0u);
    if (t >= 0 && t < T_LEN)
      v = *(const uint2*)(h3u + (b * T_LEN + t) * CONV_CH + c4 * 4);
    *(uint2*)(h3s + rr * APITCH + c4 * 4) = v;
  }

  const ushort* Wu = (const ushort*)(Wc) + (size_t)(ks * 6) * 8192;
#pragma unroll
  for (int it = 0; it < 4; ++it) {
    int idx = (it * 256 + tid) * 8;
    uint4 v = *(const uint4*)(Wu + idx);
    int n = idx >> 5, kloc = idx & 31;
    *(uint4*)(Bs[0] + n * BPITCH + kloc) = v;
  }
  __syncthreads();

  f16v acc0 = {}, acc1 = {}, acc2 = {}, acc3 = {};

  for (int ch = 0; ch < 6; ++ch) {
    const int p = ch & 1;
    if (ch < 5) {
      const ushort* src = Wu + (ch + 1) * 8192;
#pragma unroll
      for (int it = 0; it < 4; ++it) {
        int idx = (it * 256 + tid) * 8;
        uint4 v = *(const uint4*)(src + idx);
        int n = idx >> 5, kloc = idx & 31;
        *(uint4*)(Bs[p ^ 1] + n * BPITCH + kloc) = v;
      }
    }
#pragma unroll
    for (int s = 0; s < 2; ++s) {
      int k0 = ks * 192 + ch * 32 + s * 16;
      int kappa = k0 >> 8, i0 = k0 & 255;
      s8v a = *(const s8v*)(h3s + (wm * 32 + lm + kappa) * APITCH + i0 + half * 8);
      const short* bp = Bs[p] + (wn * 128 + lm) * BPITCH + s * 16 + half * 8;
      s8v b0 = *(const s8v*)(bp);
      s8v b1 = *(const s8v*)(bp + 32 * BPITCH);
      s8v b2 = *(const s8v*)(bp + 64 * BPITCH);
      s8v b3 = *(const s8v*)(bp + 96 * BPITCH);
      acc0 = __builtin_amdgcn_mfma_f32_32x32x16_bf16(a, b0, acc0, 0, 0, 0);
      acc1 = __builtin_amdgcn_mfma_f32_32x32x16_bf16(a, b1, acc1, 0, 0, 0);
      acc2 = __builtin_amdgcn_mfma_f32_32x32x16_bf16(a, b2, acc2, 0, 0, 0);
      acc3 = __builtin_amdgcn_mfma_f32_32x32x16_bf16(a, b3, acc3, 0, 0, 0);
    }
    __syncthreads();
  }

  const int col = lm;
#pragma unroll
  for (int nt = 0; nt < 4; ++nt) {
    int c = wn * 128 + nt * 32 + col;
    if (c >= CCEP_N) continue;
    float bq = 0.f;
    if (ks == 0) {
      float invq = 1.f / (float)((c < 111) ? (111 - c) : (c - 110));
      bq = bias[c] * invq;
    }
    const f16v* A = (nt == 0) ? &acc0 : (nt == 1) ? &acc1 : (nt == 2) ? &acc2 : &acc3;
#pragma unroll
    for (int reg = 0; reg < 16; ++reg) {
      int row = (reg & 3) + 8 * (reg >> 2) + 4 * half;
      int t = t0 + wm * 32 + row;
      if (t < T_LEN)
        P[(size_t)(b * T_LEN + t) * 224 + c] = (*A)[reg] + bq;
    }
  }
}

// ============================ fused FFT kernel (2 frames/block) ===============
// Frames tA=2u, tB=2u+1. Two packed forward FFTs (c + i*fr per frame); S_A, S_B
// Hermitian -> ONE inverse: Z = S_A + i*S_B, IFFT(Z) = C_A + i*C_B (both real).
// Odd rows stored directly; even-row contributions spilled to sbl/sbr; no atomics.
__device__ __forceinline__ float2 cmul(float2 a, float2 b) {
  return make_float2(fmaf(a.x, b.x, -(a.y * b.y)), fmaf(a.x, b.y, a.y * b.x));
}
__device__ __forceinline__ float2 cadd(float2 a, float2 b) { return make_float2(a.x + b.x, a.y + b.y); }
__device__ __forceinline__ float2 csub(float2 a, float2 b) { return make_float2(a.x - b.x, a.y - b.y); }

#define LIDX(i) ((i) + ((i) >> 2))

template <int Q, int OFF>
__device__ __forceinline__ void fwd_stage2(float2* __restrict__ A,
    float2* __restrict__ B, const float2* __restrict__ Tw, int j) {
  const int pos = j & (Q - 1);
  const int base = ((j - pos) << 2) + pos;
  float2 e1 = Tw[OFF + pos], e2 = Tw[OFF + Q + pos], e3 = Tw[OFF + 2 * Q + pos];
  const float2 w1 = make_float2(e1.x, -e1.y);
  const float2 w2 = make_float2(e2.x, -e2.y);
  const float2 w3 = make_float2(e3.x, -e3.y);
#pragma unroll
  for (int arr = 0; arr < 2; ++arr) {
    float2* X = arr ? B : A;
    float2 a = X[LIDX(base)], b = X[LIDX(base + Q)];
    float2 cc = X[LIDX(base + 2 * Q)], d = X[LIDX(base + 3 * Q)];
    float2 t0 = cadd(a, cc), t1 = csub(a, cc), t2 = cadd(b, d), bd = csub(b, d);
    float2 t3 = make_float2(bd.y, -bd.x);
    X[LIDX(base)]         = cadd(t0, t2);
    X[LIDX(base + Q)]     = cmul(cadd(t1, t3), w1);
    X[LIDX(base + 2 * Q)] = cmul(csub(t0, t2), w2);
    X[LIDX(base + 3 * Q)] = cmul(csub(t1, t3), w3);
  }
}

template <int Q, int OFF>
__device__ __forceinline__ void inv_stage_t(float2* __restrict__ X,
    const float2* __restrict__ Tw, int j) {
  const int pos = j & (Q - 1);
  const int base = ((j - pos) << 2) + pos;
  const float2 w1 = Tw[OFF + pos];
  const float2 w2 = Tw[OFF + Q + pos];
  const float2 w3 = Tw[OFF + 2 * Q + pos];
  float2 a = X[LIDX(base)];
  float2 b = cmul(X[LIDX(base + Q)], w1);
  float2 cc = cmul(X[LIDX(base + 2 * Q)], w2);
  float2 d = cmul(X[LIDX(base + 3 * Q)], w3);
  float2 t0 = cadd(a, cc), t1 = csub(a, cc), t2 = cadd(b, d), bd = csub(b, d);
  float2 t3 = make_float2(-bd.y, bd.x);
  X[LIDX(base)]         = cadd(t0, t2);
  X[LIDX(base + Q)]     = cadd(t1, t3);
  X[LIDX(base + 2 * Q)] = csub(t0, t2);
  X[LIDX(base + 3 * Q)] = csub(t1, t3);
}

__device__ __forceinline__ int rev4d(int v) {
  return ((v & 3) << 6) | (((v >> 2) & 3) << 4) | (((v >> 4) & 3) << 2) | ((v >> 6) & 3);
}

// grid (500, 8)
__global__ __launch_bounds__(256) void k_fft(const float* __restrict__ Pb,
    const float* __restrict__ z, const float2* __restrict__ twg,
    const float* __restrict__ wing, float* __restrict__ out,
    float* __restrict__ sbl, float* __restrict__ sbr) {
  const int u = blockIdx.x, b = blockIdx.y;
  const int tA = 2 * u, tB = tA + 1;
  const int btA = b * T_LEN + tA, btB = btA + 1;
  const int j = threadIdx.x;
  __shared__ float2 WlA[1280];
  __shared__ float2 WlB[1280];
  __shared__ float2 Tws[1020];
  for (int e = j; e < 1020; e += 256) Tws[e] = twg[e];

  const float* zb = z + b * 256000;
  float f0A = 0.f, fS, f1B = 0.f;
  {
    int zi0 = tA * 256 + j - 255;
    f0A = (zi0 >= 0) ? zb[zi0] : 0.f;
    fS = zb[tA * 256 + j + 1];
    int zi2 = tB * 256 + j + 1;
    f1B = (zi2 < 256000) ? zb[zi2] : 0.f;
  }
  float c1A = 0.f, c2A = 0.f, c1B = 0.f, c2B = 0.f;
  if (j >= 145) {
    int mA = btA * 224 + (j - 145), mB = btB * 224 + (j - 145);
    c1A = (Pb[mA] + Pb[mA + PSTRIDE]) + (Pb[mA + 2 * PSTRIDE] + Pb[mA + 3 * PSTRIDE]);
    c1B = (Pb[mB] + Pb[mB + PSTRIDE]) + (Pb[mB + 2 * PSTRIDE] + Pb[mB + 3 * PSTRIDE]);
  }
  if (j < 111) {
    int mA = btA * 224 + (j + 111), mB = btB * 224 + (j + 111);
    c2A = (Pb[mA] + Pb[mA + PSTRIDE]) + (Pb[mA + 2 * PSTRIDE] + Pb[mA + 3 * PSTRIDE]);
    c2B = (Pb[mB] + Pb[mB + PSTRIDE]) + (Pb[mB + 2 * PSTRIDE] + Pb[mB + 3 * PSTRIDE]);
  }
  __syncthreads();

  {
    float2 e1 = Tws[j], e2 = Tws[256 + j], e3 = Tws[512 + j];
    const float2 w1 = make_float2(e1.x, -e1.y);
    const float2 w2 = make_float2(e2.x, -e2.y);
    const float2 w3 = make_float2(e3.x, -e3.y);
    {
      float2 t0 = make_float2(c2A, f0A);
      float2 t1 = make_float2(-c2A, f0A);
      float2 t2 = make_float2(c1A, fS);
      float2 t3 = make_float2(fS, -c1A);
      WlA[LIDX(j)]       = cadd(t0, t2);
      WlA[LIDX(j + 256)] = cmul(cadd(t1, t3), w1);
      WlA[LIDX(j + 512)] = cmul(csub(t0, t2), w2);
      WlA[LIDX(j + 768)] = cmul(csub(t1, t3), w3);
    }
    {
      float2 t0 = make_float2(c2B, fS);
      float2 t1 = make_float2(-c2B, fS);
      float2 t2 = make_float2(c1B, f1B);
      float2 t3 = make_float2(f1B, -c1B);
      WlB[LIDX(j)]       = cadd(t0, t2);
      WlB[LIDX(j + 256)] = cmul(cadd(t1, t3), w1);
      WlB[LIDX(j + 512)] = cmul(csub(t0, t2), w2);
      WlB[LIDX(j + 768)] = cmul(csub(t1, t3), w3);
    }
  }
  __syncthreads();

  fwd_stage2<64, 768>(WlA, WlB, Tws, j);  __syncthreads();
  fwd_stage2<16, 960>(WlA, WlB, Tws, j);  __syncthreads();
  fwd_stage2<4, 1008>(WlA, WlB, Tws, j);  __syncthreads();

  const int base = 4 * j;
  float2 XA[4], XB[4];
  {
    float2 u0 = WlA[LIDX(base)], u1 = WlA[LIDX(base + 1)];
    float2 u2 = WlA[LIDX(base + 2)], u3 = WlA[LIDX(base + 3)];
    float2 t0 = cadd(u0, u2), t1 = csub(u0, u2), t2 = cadd(u1, u3), bd = csub(u1, u3);
    float2 t3 = make_float2(bd.y, -bd.x);
    XA[0] = cadd(t0, t2); XA[1] = cadd(t1, t3); XA[2] = csub(t0, t2); XA[3] = csub(t1, t3);
  }
  {
    float2 u0 = WlB[LIDX(base)], u1 = WlB[LIDX(base + 1)];
    float2 u2 = WlB[LIDX(base + 2)], u3 = WlB[LIDX(base + 3)];
    float2 t0 = cadd(u0, u2), t1 = csub(u0, u2), t2 = cadd(u1, u3), bd = csub(u1, u3);
    float2 t3 = make_float2(bd.y, -bd.x);
    XB[0] = cadd(t0, t2); XB[1] = cadd(t1, t3); XB[2] = csub(t0, t2); XB[3] = csub(t1, t3);
  }
#pragma unroll
  for (int q = 0; q < 4; ++q) { WlA[LIDX(base + q)] = XA[q]; WlB[LIDX(base + q)] = XB[q]; }
  __syncthreads();

  const int r0 = rev4d(j);
  const bool self0 = (r0 == 0);
  const int jp = self0 ? 0 : rev4d((256 - r0) & 255);
  float2 PA[4], PB[4];
#pragma unroll
  for (int q = 0; q < 4; ++q) { PA[q] = WlA[LIDX(4 * jp + q)]; PB[q] = WlB[LIDX(4 * jp + q)]; }
  float2 Z[4];
#pragma unroll
  for (int q = 0; q < 4; ++q) {
    float2 SA, SB;
    {
      float2 A = XA[q];
      float2 Bc = self0 ? PA[(4 - q) & 3] : PA[3 - q];
      float2 Y = make_float2(0.5f * (A.x + Bc.x), 0.5f * (A.y - Bc.y));
      float2 F = make_float2(0.5f * (A.y + Bc.y), -0.5f * (A.x - Bc.x));
      float mag = __expf(Y.x * 2.30258509299404568402f);
      float sy, cy;
      __sincosf(Y.y, &sy, &cy);
      float gr = mag * cy, gi = mag * sy;
      SA = make_float2(fmaf(F.x, gr, F.y * gi), fmaf(F.x, gi, -(F.y * gr)));
    }
    {
      float2 A = XB[q];
      float2 Bc = self0 ? PB[(4 - q) & 3] : PB[3 - q];
      float2 Y = make_float2(0.5f * (A.x + Bc.x), 0.5f * (A.y - Bc.y));
      float2 F = make_float2(0.5f * (A.y + Bc.y), -0.5f * (A.x - Bc.x));
      float mag = __expf(Y.x * 2.30258509299404568402f);
      float sy, cy;
      __sincosf(Y.y, &sy, &cy);
      float gr = mag * cy, gi = mag * sy;
      SB = make_float2(fmaf(F.x, gr, F.y * gi), fmaf(F.x, gi, -(F.y * gr)));
    }
    Z[q] = make_float2(SA.x - SB.y, SA.y + SB.x);   // S_A + i*S_B
  }
  __syncthreads();

  {
    float2 t0 = cadd(Z[0], Z[2]), t1 = csub(Z[0], Z[2]), t2 = cadd(Z[1], Z[3]), bd = csub(Z[1], Z[3]);
    float2 t3 = make_float2(-bd.y, bd.x);
    WlA[LIDX(base)]     = cadd(t0, t2);
    WlA[LIDX(base + 1)] = cadd(t1, t3);
    WlA[LIDX(base + 2)] = csub(t0, t2);
    WlA[LIDX(base + 3)] = csub(t1, t3);
  }
  __syncthreads();

  inv_stage_t<4, 1008>(WlA, Tws, j);  __syncthreads();
  inv_stage_t<16, 960>(WlA, Tws, j);  __syncthreads();
  inv_stage_t<64, 768>(WlA, Tws, j);  __syncthreads();

  {
    float2 w1 = Tws[j], w2 = Tws[256 + j], w3 = Tws[512 + j];
    float2 a = WlA[LIDX(j)];
    float2 bb = cmul(WlA[LIDX(j + 256)], w1);
    float2 cc = cmul(WlA[LIDX(j + 512)], w2);
    float2 d = cmul(WlA[LIDX(j + 768)], w3);
    float2 t0 = cadd(a, cc), t1 = csub(a, cc), t2 = cadd(bb, d), bd = csub(bb, d);
    float2 t3 = make_float2(-bd.y, bd.x);
    float2 Cj    = cadd(t0, t2);   // C[j]     -> corr n1 = 511-j (r-part)
    float2 Cj256 = cadd(t1, t3);   // C[j+256] -> corr n2 = 255-j (l-part)
    int n1 = 511 - j, n2 = 255 - j;
    float wn1 = wing[n1], wn2 = wing[n2];
    float vA_l = Cj256.x * wn2;                 // even row tA contribution (l)
    float vAB  = Cj.x * wn1 + Cj256.y * wn2;    // odd row tB: A.r + B.l (owned)
    float vB_r = Cj.y * wn1;                    // even row tB+1 contribution (r)
    out[(b * T_LEN + tB) * 256 + n2] = vAB;
    int su = (b * 500 + u) * 256 + n2;
    sbl[su] = vA_l;
    sbr[su] = vB_r;
  }
}

// ---- even rows: out[b, 2u, n] = l(2u) + r(2u-1 mod 1000) ---------------------
__global__ __launch_bounds__(256) void k_even(const float* __restrict__ sbl,
    const float* __restrict__ sbr, float* __restrict__ out) {
  int idx = blockIdx.x * 256 + threadIdx.x;   // 1,024,000
  int n = idx & 255;
  int bu = idx >> 8;                          // b*500 + u
  int u = bu % 500, b = bu / 500;
  int up = (u == 0) ? 499 : u - 1;
  out[(b * T_LEN + 2 * u) * 256 + n] = sbl[idx] + sbr[(b * 500 + up) * 256 + n];
}

extern "C" void kernel_launch(void* const* d_in, const int* in_sizes, int n_in,
                              void* d_out, int out_size, void* d_ws, size_t ws_size,
                              hipStream_t stream) {
  const float* x  = (const float*)d_in[0];
  const float* z  = (const float*)d_in[1];
  const float* W1 = (const float*)d_in[2];
  const float* b1 = (const float*)d_in[3];
  const float* W2 = (const float*)d_in[4];
  const float* b2 = (const float*)d_in[5];
  const float* W3 = (const float*)d_in[6];
  const float* b3 = (const float*)d_in[7];
  const float* W4 = (const float*)d_in[8];
  const float* b4 = (const float*)d_in[9];

  float* ws   = (float*)d_ws;
  __hip_bfloat16* h3bf = (__hip_bfloat16*)ws;              // 1,024,000 f32 slots
  float* Pb   = ws + 1024000;            // 4 x 1,792,000 = 7,168,000
  float* sbl  = ws + 8192000;            // 1,024,000
  float* sbr  = ws + 9216000;            // 1,024,000
  float* Wt1  = ws + 10240000;           //    61,440
  float* Wt2  = ws + 10301440;           //    24,576
  float* Wt3  = ws + 10326016;           //    24,576
  __hip_bfloat16* Wc = (__hip_bfloat16*)(ws + 10350592);   // 98,304 f32 slots
  float2* twTab = (float2*)(ws + 10448896);                // 1020 float2
  float* winTab = ws + 10450944;                           // 512
  float* out = (float*)d_out;

  dim3 blk(256);
  k_prep<<<1206, blk, 0, stream>>>(W1, W2, W3, W4, Wt1, Wt2, Wt3, Wc,
                                   twTab, winTab);

  dim3 cgrid10(T_LEN / 10, B_N);   // (100, 8)
  k_convall<<<cgrid10, blk, 0, stream>>>(x, Wt1, b1, Wt2, b2, Wt3, b3, h3bf);
  dim3 g4(16, B_N, 4);
  k_conv4m<<<g4, blk, 0, stream>>>(h3bf, Wc, b4, Pb);
  dim3 gf(T_LEN / 2, B_N);         // (500, 8)
  k_fft<<<gf, blk, 0, stream>>>(Pb, z, twTab, winTab, out, sbl, sbr);
  k_even<<<4000, blk, 0, stream>>>(sbl, sbr, out);
}